// Round 1
// baseline (117.720 us; speedup 1.0000x reference)
//
#include <hip/hip_runtime.h>

typedef __attribute__((ext_vector_type(8))) short bf16x8;
typedef __attribute__((ext_vector_type(4))) float f32x4;

#define SL 512
#define D_EMB 512
#define LN 100
#define NP 112           // filters padded to 7 n-tiles
#define MT 128           // t-rows per block
#define BTHREADS 256
#define ESTR 72          // LDS row stride (64 data + 8 pad bf16)
#define FBF_ELEMS (NP * 6144)  // 112 * (1536+2048+2560)

__device__ inline unsigned short f2bf(float x) {
    unsigned int u = __float_as_uint(x);
    u = u + 0x7FFFu + ((u >> 16) & 1u);   // round-to-nearest-even
    return (unsigned short)(u >> 16);
}
__device__ inline unsigned int pack2(float a, float b) {
    return (unsigned int)f2bf(a) | ((unsigned int)f2bf(b) << 16);
}

// ---- filters f32 -> bf16 (rows padded to 112 with zeros) -------------------
__global__ void cvt_filters(const float* __restrict__ f3,
                            const float* __restrict__ f4,
                            const float* __restrict__ f5,
                            unsigned short* __restrict__ fbf) {
    const int wz = blockIdx.y;
    const int l  = blockIdx.x;                  // 0..111
    const int Kw = (3 + wz) * D_EMB;
    const float* src = (wz == 0) ? f3 : (wz == 1 ? f4 : f5);
    const int base = (wz == 0) ? 0 : (wz == 1 ? NP * 1536 : NP * (1536 + 2048));
    for (int k = threadIdx.x; k < Kw; k += blockDim.x) {
        float v = (l < LN) ? src[l * Kw + k] : 0.0f;
        fbf[base + (size_t)l * Kw + k] = f2bf(v);
    }
}

// ---- fused gather + conv + bias + relu + max-pool --------------------------
__global__ __launch_bounds__(BTHREADS, 2)
void conv_pool(const int* __restrict__ words,
               const float* __restrict__ emb,
               const unsigned short* __restrict__ fbf,
               const float* __restrict__ b3,
               const float* __restrict__ b4,
               const float* __restrict__ b5,
               unsigned int* __restrict__ pooled) {
    const int wz   = blockIdx.z;
    const int w    = 3 + wz;
    const int Kw   = w * D_EMB;
    const int b    = blockIdx.y;
    const int t0   = blockIdx.x * MT;
    const int rows = MT + w - 1;
    const int tid  = threadIdx.x;
    const int lane = tid & 63;
    const int wv   = tid >> 6;

    __shared__ unsigned short emb_c[132 * ESTR];
    __shared__ unsigned short flt_c[NP * ESTR];
    __shared__ int wrow[132];

    if (tid < rows) {
        int t = t0 + tid;
        wrow[tid] = (t < SL) ? words[b * SL + t] : -1;
    }

    f32x4 acc[2][7] = {};
    const int fbase = (wz == 0) ? 0 : (wz == 1 ? NP * 1536 : NP * (1536 + 2048));

    __syncthreads();  // wrow ready

    for (int dc = 0; dc < D_EMB; dc += 64) {
        // stage emb rows [rows][dc..dc+63] f32 -> bf16 into LDS
        for (int s = tid; s < rows * 8; s += BTHREADS) {
            int r  = s >> 3;
            int c8 = (s & 7) * 8;
            uint4 outv;
            int widx = wrow[r];
            if (widx >= 0) {
                const float4* e4 =
                    reinterpret_cast<const float4*>(emb + (size_t)widx * D_EMB + dc + c8);
                float4 lo = e4[0], hi = e4[1];
                outv.x = pack2(lo.x, lo.y);
                outv.y = pack2(lo.z, lo.w);
                outv.z = pack2(hi.x, hi.y);
                outv.w = pack2(hi.z, hi.w);
            } else {
                outv = make_uint4(0u, 0u, 0u, 0u);
            }
            *reinterpret_cast<uint4*>(&emb_c[r * ESTR + c8]) = outv;
        }
        for (int p = 0; p < w; ++p) {
            __syncthreads();  // prev flt reads done; publishes emb writes at p==0
            // stage filter chunk [112][64]
            for (int s = tid; s < NP * 8; s += BTHREADS) {
                int l  = s >> 3;
                int c8 = (s & 7) * 8;
                uint4 v = *reinterpret_cast<const uint4*>(
                    &fbf[fbase + (size_t)l * Kw + p * D_EMB + dc + c8]);
                *reinterpret_cast<uint4*>(&flt_c[l * ESTR + c8]) = v;
            }
            __syncthreads();  // flt published
            #pragma unroll
            for (int kk = 0; kk < 64; kk += 32) {
                const int kb = kk + (lane >> 4) * 8;
                const int ar = wv * 32 + (lane & 15) + p;
                bf16x8 a0 = *reinterpret_cast<const bf16x8*>(&emb_c[ar * ESTR + kb]);
                bf16x8 a1 = *reinterpret_cast<const bf16x8*>(&emb_c[(ar + 16) * ESTR + kb]);
                #pragma unroll
                for (int n = 0; n < 7; ++n) {
                    bf16x8 bf = *reinterpret_cast<const bf16x8*>(
                        &flt_c[(n * 16 + (lane & 15)) * ESTR + kb]);
                    acc[0][n] = __builtin_amdgcn_mfma_f32_16x16x32_bf16(a0, bf, acc[0][n], 0, 0, 0);
                    acc[1][n] = __builtin_amdgcn_mfma_f32_16x16x32_bf16(a1, bf, acc[1][n], 0, 0, 0);
                }
            }
        }
        __syncthreads();  // emb_c reads done before next dc overwrites
    }

    // epilogue: bias + relu + max over this block's 128 t rows, then atomicMax
    const float* biasw = (wz == 0) ? b3 : (wz == 1 ? b4 : b5);
    #pragma unroll
    for (int n = 0; n < 7; ++n) {
        int l = n * 16 + (lane & 15);
        float bv = (l < LN) ? biasw[l] : 0.0f;
        float m = 0.0f;  // relu floor
        #pragma unroll
        for (int mt = 0; mt < 2; ++mt)
            #pragma unroll
            for (int j = 0; j < 4; ++j)
                m = fmaxf(m, acc[mt][n][j] + bv);
        m = fmaxf(m, __shfl_xor(m, 16));
        m = fmaxf(m, __shfl_xor(m, 32));
        if (lane < 16 && l < LN)
            atomicMax(&pooled[(size_t)b * 300 + wz * 100 + l], __float_as_uint(m));
    }
}

// ---- final [64,300] x [300,10] ---------------------------------------------
__global__ __launch_bounds__(64)
void out_gemm(const unsigned int* __restrict__ pooled,
              const float* __restrict__ W,
              float* __restrict__ out) {
    int b = blockIdx.x;
    __shared__ float p[300];
    for (int i = threadIdx.x; i < 300; i += 64)
        p[i] = __uint_as_float(pooled[b * 300 + i]);
    __syncthreads();
    if (threadIdx.x < 10) {
        float s = 0.f;
        for (int c = 0; c < 300; ++c)
            s += p[c] * W[c * 10 + threadIdx.x];
        out[b * 10 + threadIdx.x] = s;
    }
}

extern "C" void kernel_launch(void* const* d_in, const int* in_sizes, int n_in,
                              void* d_out, int out_size, void* d_ws, size_t ws_size,
                              hipStream_t stream) {
    const int*   words = (const int*)d_in[0];
    const float* Emb   = (const float*)d_in[1];
    const float* outW  = (const float*)d_in[2];
    const float* f3    = (const float*)d_in[3];
    const float* b3    = (const float*)d_in[4];
    const float* f4    = (const float*)d_in[5];
    const float* b4    = (const float*)d_in[6];
    const float* f5    = (const float*)d_in[7];
    const float* b5    = (const float*)d_in[8];
    float* out = (float*)d_out;

    unsigned short* fbf    = (unsigned short*)d_ws;
    unsigned int*   pooled = (unsigned int*)((char*)d_ws + (size_t)FBF_ELEMS * 2);

    hipMemsetAsync(pooled, 0, 64 * 300 * sizeof(float), stream);
    cvt_filters<<<dim3(NP, 3), 256, 0, stream>>>(f3, f4, f5, fbf);
    conv_pool<<<dim3(SL / MT, 64, 3), BTHREADS, 0, stream>>>(words, Emb, fbf, b3, b4, b5, pooled);
    out_gemm<<<64, 64, 0, stream>>>(pooled, outW, out);
}

// Round 2
// 91.831 us; speedup vs baseline: 1.2819x; 1.2819x over previous
//
#include <hip/hip_runtime.h>

typedef __attribute__((ext_vector_type(8))) short bf16x8;
typedef __attribute__((ext_vector_type(4))) float f32x4;

#define SL 512
#define SLP 520              // padded seq rows per batch (zero rows 512..519)
#define D_EMB 512
#define LN 100
#define NP 112               // filters padded to 7 n-tiles
#define MT 128               // t-rows per block
#define CHUNK_USH 7168       // 112 rows * 64 bf16 per filter chunk
#define FBF_BYTES (96 * 14336)
#define EMB_OFF FBF_BYTES
#define EMB_BYTES (64 * SLP * 512 * 2)
#define POOL_OFF (EMB_OFF + EMB_BYTES)

__device__ inline unsigned short f2bf(float x) {
    unsigned int u = __float_as_uint(x);
    u = u + 0x7FFFu + ((u >> 16) & 1u);   // RNE
    return (unsigned short)(u >> 16);
}
__device__ inline unsigned int pack2(float a, float b) {
    return (unsigned int)f2bf(a) | ((unsigned int)f2bf(b) << 16);
}

__device__ __forceinline__ void gload16(void* lds, const void* g) {
    __builtin_amdgcn_global_load_lds(
        (const __attribute__((address_space(1))) unsigned int*)g,
        (__attribute__((address_space(3))) unsigned int*)lds, 16, 0, 0);
}

// ---- filters f32 -> bf16, chunked per (dc,p) as [112][8 x 16B], source-side
// XOR-swizzle: store position u' holds logical unit u = u' ^ (row&7) ----------
__global__ __launch_bounds__(256)
void cvt_filters(const float* __restrict__ f3, const float* __restrict__ f4,
                 const float* __restrict__ f5, unsigned short* __restrict__ fbf) {
    int id = blockIdx.x * 256 + threadIdx.x;      // < 96*896
    int c  = id / 896, rr = id - c * 896;
    int l  = rr >> 3, up = rr & 7;
    int wz, cc;
    if (c < 24)      { wz = 0; cc = c; }
    else if (c < 56) { wz = 1; cc = c - 24; }
    else             { wz = 2; cc = c - 56; }
    int w  = 3 + wz;
    int dc = cc / w, p = cc - dc * w;
    int u  = up ^ (l & 7);
    uint4 ov = make_uint4(0u, 0u, 0u, 0u);
    if (l < LN) {
        const float* src = (wz == 0) ? f3 : (wz == 1 ? f4 : f5);
        const float4* s4 = (const float4*)(src + (size_t)l * (w * 512) + p * 512 + dc * 64 + u * 8);
        float4 lo = s4[0], hi = s4[1];
        ov.x = pack2(lo.x, lo.y); ov.y = pack2(lo.z, lo.w);
        ov.z = pack2(hi.x, hi.y); ov.w = pack2(hi.z, hi.w);
    }
    *(uint4*)(fbf + (size_t)c * CHUNK_USH + l * 64 + up * 8) = ov;
}

// ---- gather + convert: embseq[b][t][d] bf16, zero rows for t >= SL ----------
__global__ __launch_bounds__(256)
void emb_gather(const int* __restrict__ words, const float* __restrict__ emb,
                unsigned short* __restrict__ embseq) {
    int r    = blockIdx.x * 4 + (threadIdx.x >> 6);   // global row < 64*SLP
    int lane = threadIdx.x & 63;
    int b    = r / SLP, t = r - b * SLP;
    uint4 ov = make_uint4(0u, 0u, 0u, 0u);
    if (t < SL) {
        int widx = words[b * SL + t];
        const float4* s4 = (const float4*)(emb + (size_t)widx * 512 + lane * 8);
        float4 lo = s4[0], hi = s4[1];
        ov.x = pack2(lo.x, lo.y); ov.y = pack2(lo.z, lo.w);
        ov.z = pack2(hi.x, hi.y); ov.w = pack2(hi.z, hi.w);
    }
    *(uint4*)(embseq + (size_t)r * 512 + lane * 8) = ov;
}

// ---- fused conv + bias + relu + max-pool, double-buffered global_load_lds ---
__global__ __launch_bounds__(256, 2)
void conv_pool(const unsigned short* __restrict__ embseq,
               const unsigned short* __restrict__ fbf,
               const float* __restrict__ b3, const float* __restrict__ b4,
               const float* __restrict__ b5, unsigned int* __restrict__ pooled) {
    const int wz = blockIdx.z, w = 3 + wz;
    const int b  = blockIdx.y;
    const int t0 = blockIdx.x * MT;
    const int tid = threadIdx.x, lane = tid & 63, wv = tid >> 6;
    const int NS = 8 * w;
    const int cbase = (wz == 0) ? 0 : (wz == 1 ? 24 : 56);

    __shared__ __align__(16) unsigned short As[2][136 * 64];
    __shared__ __align__(16) unsigned short Bs[2][112 * 64];

    const unsigned short* embB = embseq + ((size_t)(b * SLP + t0)) * 512;

    #define STAGE_B(chunk, buf)                                                   \
        do {                                                                      \
            const unsigned short* _g = fbf + (size_t)(cbase + (chunk)) * CHUNK_USH;\
            _Pragma("unroll")                                                     \
            for (int _j = 0; _j < 4; ++_j) {                                      \
                int _k = tid + _j * 256;                                          \
                if (_k < 896) gload16(&Bs[buf][(_k >> 6) << 9], _g + _k * 8);     \
            }                                                                     \
        } while (0)

    #define STAGE_A(dcv, buf)                                                     \
        do {                                                                      \
            _Pragma("unroll")                                                     \
            for (int _j = 0; _j < 5; ++_j) {                                      \
                int _k = tid + _j * 256;                                          \
                if (_k < 1088) {                                                  \
                    int _row = _k >> 3, _up = _k & 7, _u = _up ^ (_row & 7);      \
                    gload16(&As[buf][(_k >> 6) << 9],                             \
                            embB + (size_t)_row * 512 + (dcv) * 64 + _u * 8);     \
                }                                                                 \
            }                                                                     \
        } while (0)

    STAGE_A(0, 0);
    STAGE_B(0, 0);
    __syncthreads();

    f32x4 acc[2][7] = {};
    int p = 0, dc = 0;
    for (int s = 0; s < NS; ++s) {
        int np = (p + 1 == w) ? 0 : p + 1;
        if (s + 1 < NS) {
            STAGE_B(s + 1, (s + 1) & 1);
            if (np == 0) STAGE_A(dc + 1, (dc + 1) & 1);
        }
        const char* Ab = (const char*)As[dc & 1];
        const char* Bb = (const char*)Bs[s & 1];
        const int ar0 = (wv << 5) + (lane & 15) + p;
        const int ar1 = ar0 + 16;
        #pragma unroll
        for (int kk = 0; kk < 2; ++kk) {
            const int kb2 = kk * 64 + ((lane >> 4) << 4);  // byte col within 128B row
            bf16x8 a0 = *(const bf16x8*)(Ab + ar0 * 128 + (kb2 ^ ((ar0 & 7) << 4)));
            bf16x8 a1 = *(const bf16x8*)(Ab + ar1 * 128 + (kb2 ^ ((ar1 & 7) << 4)));
            #pragma unroll
            for (int n = 0; n < 7; ++n) {
                const int l = (n << 4) + (lane & 15);
                bf16x8 bf = *(const bf16x8*)(Bb + l * 128 + (kb2 ^ ((l & 7) << 4)));
                acc[0][n] = __builtin_amdgcn_mfma_f32_16x16x32_bf16(a0, bf, acc[0][n], 0, 0, 0);
                acc[1][n] = __builtin_amdgcn_mfma_f32_16x16x32_bf16(a1, bf, acc[1][n], 0, 0, 0);
            }
        }
        if (np == 0) ++dc;
        p = np;
        __syncthreads();
    }

    const float* biasw = (wz == 0) ? b3 : (wz == 1 ? b4 : b5);
    #pragma unroll
    for (int n = 0; n < 7; ++n) {
        int l = (n << 4) + (lane & 15);
        float bv = (l < LN) ? biasw[l] : 0.0f;
        float m = 0.0f;   // relu floor
        #pragma unroll
        for (int mt = 0; mt < 2; ++mt)
            #pragma unroll
            for (int j = 0; j < 4; ++j)
                m = fmaxf(m, acc[mt][n][j] + bv);
        m = fmaxf(m, __shfl_xor(m, 16));
        m = fmaxf(m, __shfl_xor(m, 32));
        if (lane < 16 && l < LN)
            atomicMax(&pooled[(size_t)b * 300 + wz * 100 + l], __float_as_uint(m));
    }
    #undef STAGE_A
    #undef STAGE_B
}

// ---- final [64,300] x [300,10] ---------------------------------------------
__global__ __launch_bounds__(64)
void out_gemm(const unsigned int* __restrict__ pooled,
              const float* __restrict__ W, float* __restrict__ out) {
    int b = blockIdx.x;
    __shared__ float pshared[300];
    for (int i = threadIdx.x; i < 300; i += 64)
        pshared[i] = __uint_as_float(pooled[b * 300 + i]);
    __syncthreads();
    if (threadIdx.x < 10) {
        float s = 0.f;
        for (int c = 0; c < 300; ++c)
            s += pshared[c] * W[c * 10 + threadIdx.x];
        out[b * 10 + threadIdx.x] = s;
    }
}

extern "C" void kernel_launch(void* const* d_in, const int* in_sizes, int n_in,
                              void* d_out, int out_size, void* d_ws, size_t ws_size,
                              hipStream_t stream) {
    const int*   words = (const int*)d_in[0];
    const float* Emb   = (const float*)d_in[1];
    const float* outW  = (const float*)d_in[2];
    const float* f3    = (const float*)d_in[3];
    const float* b3    = (const float*)d_in[4];
    const float* f4    = (const float*)d_in[5];
    const float* b4    = (const float*)d_in[6];
    const float* f5    = (const float*)d_in[7];
    const float* b5    = (const float*)d_in[8];
    float* out = (float*)d_out;

    unsigned short* fbf    = (unsigned short*)d_ws;
    unsigned short* embseq = (unsigned short*)((char*)d_ws + EMB_OFF);
    unsigned int*   pooled = (unsigned int*)((char*)d_ws + POOL_OFF);

    hipMemsetAsync(pooled, 0, 64 * 300 * sizeof(float), stream);
    cvt_filters<<<336, 256, 0, stream>>>(f3, f4, f5, fbf);
    emb_gather<<<(64 * SLP) / 4, 256, 0, stream>>>(words, Emb, embseq);
    conv_pool<<<dim3(SL / MT, 64, 3), 256, 0, stream>>>(embseq, fbf, b3, b4, b5, pooled);
    out_gemm<<<64, 64, 0, stream>>>(pooled, outW, out);
}